// Round 12
// baseline (4973.551 us; speedup 1.0000x reference)
//
#include <hip/hip_runtime.h>
#include <hip/hip_bf16.h>
#include <cstdint>
#include <cstddef>
#include <type_traits>

#define B_ALL 256
#define T_LEN 512
#define D_INP 64
#define HD    128
#define G4    512            // 4*H
#define NC    12
#define BCH   128            // batch per chunk
#define ROWS  (BCH * T_LEN)  // 65536 rows per chunk

// ---------- helpers ----------
__device__ __forceinline__ float bf2f(unsigned short u) {
    union { unsigned int i; float f; } v; v.i = ((unsigned int)u) << 16; return v.f;
}
__device__ __forceinline__ unsigned short f2bf(float f) {
    union { float f; unsigned int i; } v; v.f = f;
    unsigned int r = v.i + 0x7FFFu + ((v.i >> 16) & 1u);  // round-nearest-even
    return (unsigned short)(r >> 16);
}
__device__ __forceinline__ float sigf(float x) { return 1.0f / (1.0f + __expf(-x)); }
__device__ __forceinline__ float tanh_f(float x) {
    float xx = fminf(15.0f, fmaxf(-15.0f, x));
    float e = __expf(2.0f * xx);
    return (e - 1.0f) / (e + 1.0f);
}

// LDS-only barrier: drains lgkmcnt but leaves global loads/stores in flight.
#define LDS_BARRIER() asm volatile("s_waitcnt lgkmcnt(0)\n\ts_barrier" ::: "memory")

using bf16x8 = __attribute__((ext_vector_type(8))) short;
using f32x4  = __attribute__((ext_vector_type(4))) float;

// XOR swizzle for [R][32] bf16 LDS tiles (64B rows).
__device__ __forceinline__ int swz(int r, int kb) {
    return (r * 64 + kb) ^ ((r & 3) << 4);
}

// ---------- W split: fp32 -> hi/lo bf16 pair (hi+lo ~ fp32 exact) ----------
__global__ __launch_bounds__(256)
void split_w(const float* __restrict__ w, unsigned short* __restrict__ hi,
             unsigned short* __restrict__ lo, int n)
{
    int i = blockIdx.x * 256 + threadIdx.x;
    if (i < n) {
        float f = w[i];
        unsigned short h = f2bf(f);
        hi[i] = h;
        lo[i] = f2bf(f - bf2f(h));
    }
}

// ---------- Whh: permute rows for in-register nonlinearity + split hi/lo ----------
// New row r' = wv*32 + half*16 + q*4 + g  maps to original row g*128 + hdim,
// hdim = wv*8 + half*4 + q. Then MFMA C-frag reg r of lane l (wave wv) holds
// gate g=r of hdim(wv, half, q=l>>4) at batch col b=l&15 — the 4 gates of one
// hdim land in ONE lane's accumulator.
__global__ __launch_bounds__(256)
void perm_split_whh(const float* __restrict__ whh,   // [2][512][128]
                    unsigned short* __restrict__ hi,
                    unsigned short* __restrict__ lo)
{
    int i = blockIdx.x * 256 + threadIdx.x;
    if (i >= 2 * G4 * HD) return;
    int k  = i & 127;
    int rp = (i >> 7) & 511;
    int d  = i >> 16;
    int wv = rp >> 5, rem = rp & 31, half = rem >> 4, rem2 = rem & 15;
    int q = rem2 >> 2, g = rem2 & 3;
    int hdim = wv * 8 + half * 4 + q;
    float f = whh[((size_t)d * G4 + g * HD + hdim) * HD + k];
    unsigned short h = f2bf(f);
    hi[i] = h;
    lo[i] = f2bf(f - bf2f(h));
}

// ---------- gates GEMM (MFMA, split-precision bf16) ----------
// R12: epilogue writes GATE-INTERLEAVED columns: col' = dir*512 + hdim*4 + g
// so the recurrence loads the 4 gate biases of one hdim as ONE ushort4.
template <int TERMS, typename TA>
__global__ __launch_bounds__(256)
void gates_gemm_mfma(const TA* __restrict__ A,
                     const unsigned short* __restrict__ Whi_g,
                     const unsigned short* __restrict__ Wlo_g,
                     const float* __restrict__ bias,
                     const int* __restrict__ lens,
                     unsigned short* __restrict__ out, int K)
{
    int row0 = blockIdx.x * 128;
    int col0 = blockIdx.y * 128;
    int bl = row0 >> 9;
    int t0 = row0 & (T_LEN - 1);
    if (t0 >= lens[bl]) return;

    __shared__ __align__(16) char smem[TERMS == 3 ? 32768 : 24576];
    char* sAhi = smem;                 // [128][32] bf16, swizzled
    char* sWhi = smem + 8192;
    char* sWlo = smem + 16384;
    char* sAlo = (TERMS == 3) ? smem + 24576 : smem;

    int tid = threadIdx.x;
    int l   = tid & 63;
    int w   = tid >> 6;
    int wr  = (w >> 1) * 64;
    int wc  = (w & 1) * 64;

    f32x4 acc[4][4];
#pragma unroll
    for (int mi = 0; mi < 4; ++mi)
#pragma unroll
        for (int ni = 0; ni < 4; ++ni) acc[mi][ni] = (f32x4){0.f, 0.f, 0.f, 0.f};

    int fr = l & 15;
    int fk = (l >> 4) * 16;

    for (int kt = 0; kt < K; kt += 32) {
#pragma unroll
        for (int q = 0; q < 2; ++q) {
            int c = tid + 256 * q;
            int r = c >> 2, kc = c & 3;
            size_t gi = (size_t)(col0 + r) * K + kt + kc * 8;
            *(uint4*)(sWhi + swz(r, kc * 16)) = *(const uint4*)&Whi_g[gi];
            *(uint4*)(sWlo + swz(r, kc * 16)) = *(const uint4*)&Wlo_g[gi];
        }
        if constexpr (std::is_same<TA, unsigned short>::value) {
#pragma unroll
            for (int q = 0; q < 2; ++q) {
                int c = tid + 256 * q;
                int r = c >> 2, kc = c & 3;
                *(uint4*)(sAhi + swz(r, kc * 16)) =
                    *(const uint4*)&A[(size_t)(row0 + r) * K + kt + kc * 8];
            }
        } else {
#pragma unroll
            for (int q = 0; q < 4; ++q) {
                int c = tid + 256 * q;
                int r = c >> 3, kc = c & 7;
                float4 f = *(const float4*)&A[(size_t)(row0 + r) * K + kt + kc * 4];
                ushort4 h, lo;
                h.x = f2bf(f.x); lo.x = f2bf(f.x - bf2f(h.x));
                h.y = f2bf(f.y); lo.y = f2bf(f.y - bf2f(h.y));
                h.z = f2bf(f.z); lo.z = f2bf(f.z - bf2f(h.z));
                h.w = f2bf(f.w); lo.w = f2bf(f.w - bf2f(h.w));
                *(ushort4*)(sAhi + swz(r, kc * 8)) = h;
                *(ushort4*)(sAlo + swz(r, kc * 8)) = lo;
            }
        }
        __syncthreads();

        bf16x8 ah[4], al[4], bh[4], bl4[4];
#pragma unroll
        for (int mi = 0; mi < 4; ++mi) {
            int off = swz(wr + mi * 16 + fr, fk);
            ah[mi] = *(const bf16x8*)(sAhi + off);
            if (TERMS == 3) al[mi] = *(const bf16x8*)(sAlo + off);
        }
#pragma unroll
        for (int ni = 0; ni < 4; ++ni) {
            int off = swz(wc + ni * 16 + fr, fk);
            bh[ni]  = *(const bf16x8*)(sWhi + off);
            bl4[ni] = *(const bf16x8*)(sWlo + off);
        }
#pragma unroll
        for (int mi = 0; mi < 4; ++mi)
#pragma unroll
            for (int ni = 0; ni < 4; ++ni) {
                acc[mi][ni] = __builtin_amdgcn_mfma_f32_16x16x32_bf16(
                    ah[mi], bh[ni], acc[mi][ni], 0, 0, 0);
                acc[mi][ni] = __builtin_amdgcn_mfma_f32_16x16x32_bf16(
                    ah[mi], bl4[ni], acc[mi][ni], 0, 0, 0);
                if (TERMS == 3)
                    acc[mi][ni] = __builtin_amdgcn_mfma_f32_16x16x32_bf16(
                        al[mi], bh[ni], acc[mi][ni], 0, 0, 0);
            }
        __syncthreads();
    }

    int r4 = (l >> 4) * 4;
#pragma unroll
    for (int ni = 0; ni < 4; ++ni) {
        int col = col0 + wc + ni * 16 + fr;
        float bj = bias[col];
        int rem  = col & 511;
        int colp = (col & 512) + (rem & 127) * 4 + (rem >> 7);   // interleaved
#pragma unroll
        for (int mi = 0; mi < 4; ++mi) {
            int row = row0 + wr + mi * 16 + r4;
            f32x4 v = acc[mi][ni];
#pragma unroll
            for (int r = 0; r < 4; ++r)
                out[(size_t)(row + r) * 1024 + colp] = f2bf(v[r] + bj);
        }
    }
}

// ---------- LSTM recurrence (R12: MFMA + in-register nonlinearity) ----------
// 16 same-dir batch elements/block, 16 waves. Per step:
//   G(512x16) = Wperm(512x128) @ H(128x16) via 16x16x32 bf16 MFMA, 3-term
//   split precision. Wperm's row permutation makes each lane's C-frag regs
//   0..3 the (i,f,g,o) gates of one hdim at batch col b=l&15 -> nonlinearity
//   entirely in registers (NO G LDS: kills R11's 6.1M bank conflicts).
//   xg biases: ONE ushort4/hdim (gate-interleaved), prefetched 1 step ahead
//   (off critical path; lgkm barrier leaves them in flight - R11's miss).
//   h: bf16 hi/lo ping-pong LDS [16][136] (2-way = free). ONE barrier/step.
__global__ __launch_bounds__(1024, 1)
void lstm_rec_mfma(const unsigned short* __restrict__ xg,   // [ROWS][1024] interleaved
                   const unsigned short* __restrict__ Whi,  // [2][512][128] permuted
                   const unsigned short* __restrict__ Wlo,
                   const int* __restrict__ lens,            // chunk-offset
                   unsigned short* __restrict__ hs,         // [ROWS][256] or null
                   float* __restrict__ hTf, float* __restrict__ hTb,
                   int bOff)
{
    int dir = blockIdx.x >> 3;
    int grp = blockIdx.x & 7;
    int tid = threadIdx.x;
    int wv  = tid >> 6;
    int l   = tid & 63;
    int fr  = l & 15;            // batch col b
    int q   = l >> 4;            // 0..3
    int hd0 = wv * 8 + q;        // hdim of acc0
    int hd1 = wv * 8 + 4 + q;    // hdim of acc1

    __shared__ unsigned short hH[2][16][136];
    __shared__ unsigned short hL[2][16][136];

    int bl = grp * 16 + fr;
    int L  = lens[bl];
    int Lmax = 0;
    for (int i = 0; i < 16; ++i) Lmax = max(Lmax, lens[grp * 16 + i]);

    // A-fragments (Wperm rows wv*32 + mi*16 + fr), loaded once
    const unsigned short* Ah = Whi + (size_t)dir * G4 * HD;
    const unsigned short* Al = Wlo + (size_t)dir * G4 * HD;
    bf16x8 a_hi[2][4], a_lo[2][4];
#pragma unroll
    for (int mi = 0; mi < 2; ++mi)
#pragma unroll
        for (int kt = 0; kt < 4; ++kt) {
            size_t a = (size_t)(wv * 32 + mi * 16 + fr) * HD + kt * 32 + q * 8;
            a_hi[mi][kt] = *(const bf16x8*)&Ah[a];
            a_lo[mi][kt] = *(const bf16x8*)&Al[a];
        }

    {
        unsigned short* pH = &hH[0][0][0];
        unsigned short* pL = &hL[0][0][0];
        for (int i = tid; i < 2 * 16 * 136; i += 1024) { pH[i] = 0; pL[i] = 0; }
    }
    float c0 = 0.f, c1 = 0.f, h0f = 0.f, h1f = 0.f;
    unsigned short h0hi = 0, h0lo = 0, h1hi = 0, h1lo = 0;
    __syncthreads();

    const unsigned short* xrow = xg + (size_t)bl * T_LEN * 1024 + dir * 512;
    // prefetch step-0 gate biases (one ushort4 per hdim)
    int tt0 = dir ? (L - 1) : 0;
    ushort4 xq0 = *(const ushort4*)&xrow[(size_t)tt0 * 1024 + hd0 * 4];
    ushort4 xq1 = *(const ushort4*)&xrow[(size_t)tt0 * 1024 + hd1 * 4];

    int cur = 0;
    for (int t = 0; t < Lmax; ++t) {
        // pin all A-frags simultaneously (loop-carried in VGPRs)
        asm volatile("" :
            "+v"(a_hi[0][0]), "+v"(a_hi[0][1]), "+v"(a_hi[0][2]), "+v"(a_hi[0][3]),
            "+v"(a_hi[1][0]), "+v"(a_hi[1][1]), "+v"(a_hi[1][2]), "+v"(a_hi[1][3]),
            "+v"(a_lo[0][0]), "+v"(a_lo[0][1]), "+v"(a_lo[0][2]), "+v"(a_lo[0][3]),
            "+v"(a_lo[1][0]), "+v"(a_lo[1][1]), "+v"(a_lo[1][2]), "+v"(a_lo[1][3]));

        // ---- MFMA: G = Wperm @ H (3-term split precision) ----
        f32x4 acc0 = (f32x4){0.f, 0.f, 0.f, 0.f};
        f32x4 acc1 = (f32x4){0.f, 0.f, 0.f, 0.f};
#pragma unroll
        for (int kt = 0; kt < 4; ++kt) {
            bf16x8 bhi = *(const bf16x8*)&hH[cur][fr][kt * 32 + q * 8];
            bf16x8 blo = *(const bf16x8*)&hL[cur][fr][kt * 32 + q * 8];
            acc0 = __builtin_amdgcn_mfma_f32_16x16x32_bf16(a_hi[0][kt], bhi, acc0, 0, 0, 0);
            acc0 = __builtin_amdgcn_mfma_f32_16x16x32_bf16(a_hi[0][kt], blo, acc0, 0, 0, 0);
            acc0 = __builtin_amdgcn_mfma_f32_16x16x32_bf16(a_lo[0][kt], bhi, acc0, 0, 0, 0);
            acc1 = __builtin_amdgcn_mfma_f32_16x16x32_bf16(a_hi[1][kt], bhi, acc1, 0, 0, 0);
            acc1 = __builtin_amdgcn_mfma_f32_16x16x32_bf16(a_hi[1][kt], blo, acc1, 0, 0, 0);
            acc1 = __builtin_amdgcn_mfma_f32_16x16x32_bf16(a_lo[1][kt], bhi, acc1, 0, 0, 0);
        }

        // ---- nonlinearity: in-register, 2 hdims/lane ----
        int tt = dir ? (L - 1 - t) : t;
        bool v = (t < L);
        if (v) {
            float gi = acc0[0] + bf2f(xq0.x);
            float gf = acc0[1] + bf2f(xq0.y);
            float gg = acc0[2] + bf2f(xq0.z);
            float go = acc0[3] + bf2f(xq0.w);
            float I = sigf(gi), F = sigf(gf), Gg = tanh_f(gg), O = sigf(go);
            c0 = F * c0 + I * Gg;
            float hn = O * tanh_f(c0);
            h0f = hn;
            h0hi = f2bf(hn);
            h0lo = f2bf(hn - bf2f(h0hi));

            gi = acc1[0] + bf2f(xq1.x);
            gf = acc1[1] + bf2f(xq1.y);
            gg = acc1[2] + bf2f(xq1.z);
            go = acc1[3] + bf2f(xq1.w);
            I = sigf(gi); F = sigf(gf); Gg = tanh_f(gg); O = sigf(go);
            c1 = F * c1 + I * Gg;
            hn = O * tanh_f(c1);
            h1f = hn;
            h1hi = f2bf(hn);
            h1lo = f2bf(hn - bf2f(h1hi));

            if (hs) {
                size_t rb = (size_t)(bl * T_LEN + tt) * 256 + dir * HD;
                hs[rb + hd0] = h0hi;
                hs[rb + hd1] = h1hi;
            }
        }

        // prefetch next step's biases (in flight across barrier + MFMA)
        int tn = t + 1;
        if (tn < L) {
            int ttn = dir ? (L - 1 - tn) : tn;
            xq0 = *(const ushort4*)&xrow[(size_t)ttn * 1024 + hd0 * 4];
            xq1 = *(const ushort4*)&xrow[(size_t)ttn * 1024 + hd1 * 4];
        }

        // write h (frozen lanes rewrite their last value) to the other buffer
        int nxt = cur ^ 1;
        hH[nxt][fr][hd0] = h0hi; hL[nxt][fr][hd0] = h0lo;
        hH[nxt][fr][hd1] = h1hi; hL[nxt][fr][hd1] = h1lo;
        LDS_BARRIER();   // the ONLY barrier per step
        cur = nxt;
    }

    if (hTf) {
        float* dst = dir ? hTb : hTf;
        dst[(size_t)(bOff + bl) * HD + hd0] = h0f;
        dst[(size_t)(bOff + bl) * HD + hd1] = h1f;
    }
}

// ---------- final FC + log_softmax ----------
__global__ __launch_bounds__(256)
void fc_lsm(const float* __restrict__ hTf, const float* __restrict__ hTb,
            const float* __restrict__ Wfc, const float* __restrict__ bfc,
            float* __restrict__ out)
{
    int b = threadIdx.x;
    const float* hb = hTb + (size_t)b * HD;
    const float* hf = hTf + (size_t)b * HD;
    float l[NC];
#pragma unroll
    for (int cc = 0; cc < NC; ++cc) {
        const float* wr = Wfc + cc * 256;
        float acc = bfc[cc];
        for (int k = 0; k < HD; k += 4) {
            acc += hb[k] * wr[k] + hb[k + 1] * wr[k + 1]
                 + hb[k + 2] * wr[k + 2] + hb[k + 3] * wr[k + 3];
            acc += hf[k] * wr[128 + k] + hf[k + 1] * wr[128 + k + 1]
                 + hf[k + 2] * wr[128 + k + 2] + hf[k + 3] * wr[128 + k + 3];
        }
        l[cc] = acc;
    }
    float m = l[0];
#pragma unroll
    for (int cc = 1; cc < NC; ++cc) m = fmaxf(m, l[cc]);
    float s = 0.0f;
#pragma unroll
    for (int cc = 0; cc < NC; ++cc) s += __expf(l[cc] - m);
    float lg = m + logf(s);
#pragma unroll
    for (int cc = 0; cc < NC; ++cc) out[(size_t)b * NC + cc] = l[cc] - lg;
}

extern "C" void kernel_launch(void* const* d_in, const int* in_sizes, int n_in,
                              void* d_out, int out_size, void* d_ws, size_t ws_size,
                              hipStream_t stream)
{
    const float* X    = (const float*)d_in[0];
    const int*   len  = (const int*)d_in[1];
    const float* Wih0 = (const float*)d_in[2];   // (2,512,64)  -> (1024,64)
    const float* Whh0 = (const float*)d_in[3];   // (2,512,128)
    const float* b0   = (const float*)d_in[4];   // (2,512) -> (1024)
    const float* Wih1 = (const float*)d_in[5];   // (2,512,256) -> (1024,256)
    const float* Whh1 = (const float*)d_in[6];
    const float* b1   = (const float*)d_in[7];
    const float* Wfc  = (const float*)d_in[8];   // (12,256)
    const float* bfc  = (const float*)d_in[9];   // (12)
    float* out = (float*)d_out;

    char* ws = (char*)d_ws;
    size_t off = 0;
    unsigned short* xg = (unsigned short*)(ws + off); off += (size_t)ROWS * 1024 * 2;
    unsigned short* h1 = (unsigned short*)(ws + off); off += (size_t)ROWS * 256 * 2;
    float* hTf = (float*)(ws + off); off += (size_t)B_ALL * HD * 4;
    float* hTb = (float*)(ws + off); off += (size_t)B_ALL * HD * 4;
    unsigned short* W0hi = (unsigned short*)(ws + off); off += 1024 * 64 * 2;
    unsigned short* W0lo = (unsigned short*)(ws + off); off += 1024 * 64 * 2;
    unsigned short* W1hi = (unsigned short*)(ws + off); off += 1024 * 256 * 2;
    unsigned short* W1lo = (unsigned short*)(ws + off); off += 1024 * 256 * 2;
    unsigned short* R0hi = (unsigned short*)(ws + off); off += 1024 * 128 * 2;  // Whh0 perm-split
    unsigned short* R0lo = (unsigned short*)(ws + off); off += 1024 * 128 * 2;
    unsigned short* R1hi = (unsigned short*)(ws + off); off += 1024 * 128 * 2;  // Whh1 perm-split
    unsigned short* R1lo = (unsigned short*)(ws + off); off += 1024 * 128 * 2;

    split_w<<<(1024 * 64 + 255) / 256, 256, 0, stream>>>(Wih0, W0hi, W0lo, 1024 * 64);
    split_w<<<(1024 * 256 + 255) / 256, 256, 0, stream>>>(Wih1, W1hi, W1lo, 1024 * 256);
    perm_split_whh<<<(1024 * 128 + 255) / 256, 256, 0, stream>>>(Whh0, R0hi, R0lo);
    perm_split_whh<<<(1024 * 128 + 255) / 256, 256, 0, stream>>>(Whh1, R1hi, R1lo);

    for (int ch = 0; ch < 2; ++ch) {
        const int* lc = len + ch * BCH;
        const float* Xc = X + (size_t)ch * BCH * T_LEN * D_INP;

        gates_gemm_mfma<3, float><<<dim3(ROWS / 128, 8), 256, 0, stream>>>(
            Xc, W0hi, W0lo, b0, lc, xg, D_INP);
        lstm_rec_mfma<<<16, 1024, 0, stream>>>(xg, R0hi, R0lo, lc, h1,
                                               nullptr, nullptr, 0);
        gates_gemm_mfma<2, unsigned short><<<dim3(ROWS / 128, 8), 256, 0, stream>>>(
            h1, W1hi, W1lo, b1, lc, xg, 2 * HD);
        lstm_rec_mfma<<<16, 1024, 0, stream>>>(xg, R1hi, R1lo, lc, nullptr,
                                               hTf, hTb, ch * BCH);
    }
    fc_lsm<<<1, 256, 0, stream>>>(hTf, hTb, Wfc, bfc, out);
}

// Round 13
// 2363.298 us; speedup vs baseline: 2.1045x; 2.1045x over previous
//
#include <hip/hip_runtime.h>
#include <hip/hip_bf16.h>
#include <cstdint>
#include <cstddef>
#include <type_traits>

#define B_ALL 256
#define T_LEN 512
#define D_INP 64
#define HD    128
#define G4    512            // 4*H
#define NC    12
#define BCH   128            // batch per chunk
#define ROWS  (BCH * T_LEN)  // 65536 rows per chunk

// ---------- helpers ----------
__device__ __forceinline__ float bf2f(unsigned short u) {
    union { unsigned int i; float f; } v; v.i = ((unsigned int)u) << 16; return v.f;
}
__device__ __forceinline__ unsigned short f2bf(float f) {
    union { float f; unsigned int i; } v; v.f = f;
    unsigned int r = v.i + 0x7FFFu + ((v.i >> 16) & 1u);  // round-nearest-even
    return (unsigned short)(r >> 16);
}
__device__ __forceinline__ float sigf(float x) { return 1.0f / (1.0f + __expf(-x)); }
__device__ __forceinline__ float tanh_f(float x) {
    float xx = fminf(15.0f, fmaxf(-15.0f, x));
    float e = __expf(2.0f * xx);
    return (e - 1.0f) / (e + 1.0f);
}

// LDS-only barrier: drains lgkmcnt but leaves global loads/stores in flight.
#define LDS_BARRIER() asm volatile("s_waitcnt lgkmcnt(0)\n\ts_barrier" ::: "memory")

using bf16x8 = __attribute__((ext_vector_type(8))) short;
using f32x4  = __attribute__((ext_vector_type(4))) float;

// XOR swizzle for [R][32] bf16 LDS tiles (64B rows).
__device__ __forceinline__ int swz(int r, int kb) {
    return (r * 64 + kb) ^ ((r & 3) << 4);
}

// ---------- W split: fp32 -> hi/lo bf16 pair (hi+lo ~ fp32 exact) ----------
__global__ __launch_bounds__(256)
void split_w(const float* __restrict__ w, unsigned short* __restrict__ hi,
             unsigned short* __restrict__ lo, int n)
{
    int i = blockIdx.x * 256 + threadIdx.x;
    if (i < n) {
        float f = w[i];
        unsigned short h = f2bf(f);
        hi[i] = h;
        lo[i] = f2bf(f - bf2f(h));
    }
}

// ---------- gates GEMM (MFMA, split-precision bf16) — proven R3 version ----------
template <int TERMS, typename TA>
__global__ __launch_bounds__(256)
void gates_gemm_mfma(const TA* __restrict__ A,
                     const unsigned short* __restrict__ Whi_g,
                     const unsigned short* __restrict__ Wlo_g,
                     const float* __restrict__ bias,
                     const int* __restrict__ lens,
                     unsigned short* __restrict__ out, int K)
{
    int row0 = blockIdx.x * 128;
    int col0 = blockIdx.y * 128;
    int bl = row0 >> 9;
    int t0 = row0 & (T_LEN - 1);
    if (t0 >= lens[bl]) return;

    __shared__ __align__(16) char smem[TERMS == 3 ? 32768 : 24576];
    char* sAhi = smem;                 // [128][32] bf16, swizzled
    char* sWhi = smem + 8192;
    char* sWlo = smem + 16384;
    char* sAlo = (TERMS == 3) ? smem + 24576 : smem;

    int tid = threadIdx.x;
    int l   = tid & 63;
    int w   = tid >> 6;
    int wr  = (w >> 1) * 64;
    int wc  = (w & 1) * 64;

    f32x4 acc[4][4];
#pragma unroll
    for (int mi = 0; mi < 4; ++mi)
#pragma unroll
        for (int ni = 0; ni < 4; ++ni) acc[mi][ni] = (f32x4){0.f, 0.f, 0.f, 0.f};

    int fr = l & 15;
    int fk = (l >> 4) * 16;

    for (int kt = 0; kt < K; kt += 32) {
#pragma unroll
        for (int q = 0; q < 2; ++q) {
            int c = tid + 256 * q;
            int r = c >> 2, kc = c & 3;
            size_t gi = (size_t)(col0 + r) * K + kt + kc * 8;
            *(uint4*)(sWhi + swz(r, kc * 16)) = *(const uint4*)&Whi_g[gi];
            *(uint4*)(sWlo + swz(r, kc * 16)) = *(const uint4*)&Wlo_g[gi];
        }
        if constexpr (std::is_same<TA, unsigned short>::value) {
#pragma unroll
            for (int q = 0; q < 2; ++q) {
                int c = tid + 256 * q;
                int r = c >> 2, kc = c & 3;
                *(uint4*)(sAhi + swz(r, kc * 16)) =
                    *(const uint4*)&A[(size_t)(row0 + r) * K + kt + kc * 8];
            }
        } else {
#pragma unroll
            for (int q = 0; q < 4; ++q) {
                int c = tid + 256 * q;
                int r = c >> 3, kc = c & 7;
                float4 f = *(const float4*)&A[(size_t)(row0 + r) * K + kt + kc * 4];
                ushort4 h, lo;
                h.x = f2bf(f.x); lo.x = f2bf(f.x - bf2f(h.x));
                h.y = f2bf(f.y); lo.y = f2bf(f.y - bf2f(h.y));
                h.z = f2bf(f.z); lo.z = f2bf(f.z - bf2f(h.z));
                h.w = f2bf(f.w); lo.w = f2bf(f.w - bf2f(h.w));
                *(ushort4*)(sAhi + swz(r, kc * 8)) = h;
                *(ushort4*)(sAlo + swz(r, kc * 8)) = lo;
            }
        }
        __syncthreads();

        bf16x8 ah[4], al[4], bh[4], bl4[4];
#pragma unroll
        for (int mi = 0; mi < 4; ++mi) {
            int off = swz(wr + mi * 16 + fr, fk);
            ah[mi] = *(const bf16x8*)(sAhi + off);
            if (TERMS == 3) al[mi] = *(const bf16x8*)(sAlo + off);
        }
#pragma unroll
        for (int ni = 0; ni < 4; ++ni) {
            int off = swz(wc + ni * 16 + fr, fk);
            bh[ni]  = *(const bf16x8*)(sWhi + off);
            bl4[ni] = *(const bf16x8*)(sWlo + off);
        }
#pragma unroll
        for (int mi = 0; mi < 4; ++mi)
#pragma unroll
            for (int ni = 0; ni < 4; ++ni) {
                acc[mi][ni] = __builtin_amdgcn_mfma_f32_16x16x32_bf16(
                    ah[mi], bh[ni], acc[mi][ni], 0, 0, 0);
                acc[mi][ni] = __builtin_amdgcn_mfma_f32_16x16x32_bf16(
                    ah[mi], bl4[ni], acc[mi][ni], 0, 0, 0);
                if (TERMS == 3)
                    acc[mi][ni] = __builtin_amdgcn_mfma_f32_16x16x32_bf16(
                        al[mi], bh[ni], acc[mi][ni], 0, 0, 0);
            }
        __syncthreads();
    }

    int r4 = (l >> 4) * 4;
#pragma unroll
    for (int ni = 0; ni < 4; ++ni) {
        int col = col0 + wc + ni * 16 + fr;
        float bj = bias[col];
#pragma unroll
        for (int mi = 0; mi < 4; ++mi) {
            int row = row0 + wr + mi * 16 + r4;
            f32x4 v = acc[mi][ni];
#pragma unroll
            for (int r = 0; r < 4; ++r)
                out[(size_t)(row + r) * 1024 + col] = f2bf(v[r] + bj);
        }
    }
}

// ---------- LSTM recurrence: proven R3/R5 structure, dual-role capable ----------
// blockIdx.x & 255 selects (dir, bl) within a role; blockIdx.x >> 8 selects
// role (0 or 1). Roles carry independent xg/lens/hs/hT pointers so ONE
// dispatch can run two INDEPENDENT 256-block recurrences co-resident
// (2 blocks/CU, independent barriers -> stalls of one block filled by the
// other's waves — unlike adding waves to one block (R6 null), the barrier
// schedules are decoupled). Inner loop byte-identical to the 519 µs R5 rec.
__global__ __launch_bounds__(512)
void lstm_rec(const unsigned short* __restrict__ xg0,
              const unsigned short* __restrict__ xg1,
              const float* __restrict__ WhhA,
              const float* __restrict__ WhhB,
              const int* __restrict__ lens0, const int* __restrict__ lens1,
              unsigned short* __restrict__ hs0, unsigned short* __restrict__ hs1,
              float* __restrict__ hTf0, float* __restrict__ hTb0,
              float* __restrict__ hTf1, float* __restrict__ hTb1,
              int bOff0, int bOff1)
{
    int role = blockIdx.x >> 8;
    int bid  = blockIdx.x & 255;
    const unsigned short* xg = role ? xg1 : xg0;
    const float* Whh  = role ? WhhB : WhhA;
    const int* lens   = role ? lens1 : lens0;
    unsigned short* hs = role ? hs1 : hs0;
    float* hTf = role ? hTf1 : hTf0;
    float* hTb = role ? hTb1 : hTb0;
    int bOff   = role ? bOff1 : bOff0;

    int dir = bid >> 7;          // 128 batch per chunk
    int bl  = bid & 127;
    int L   = lens[bl];
    int tid = threadIdx.x;
    int ks  = tid >> 7;          // k-quarter 0..3 (wave-uniform)
    int rr  = tid & 127;         // output index 0..127

    __shared__ float h_s[HD];
    __shared__ float gp[4][G4];

    float w[4][32];
#pragma unroll
    for (int g = 0; g < 4; ++g) {
        const float* wrow = Whh + ((size_t)dir * G4 + g * HD + rr) * HD + ks * 32;
#pragma unroll
        for (int k = 0; k < 32; k += 4) {
            float4 v = *(const float4*)(wrow + k);
            w[g][k] = v.x; w[g][k + 1] = v.y; w[g][k + 2] = v.z; w[g][k + 3] = v.w;
        }
    }

    if (tid < HD) h_s[tid] = 0.0f;
    float c = 0.0f, hkeep = 0.0f;
    __syncthreads();

    const unsigned short* xgb = xg + (size_t)bl * T_LEN * 1024 + (size_t)dir * G4;
    int tt   = dir ? (L - 1) : 0;
    int step = dir ? -1 : 1;

    float xv0 = 0.f, xv1 = 0.f, xv2 = 0.f, xv3 = 0.f;
    if (tid < HD) {
        const unsigned short* p = xgb + (size_t)tt * 1024;
        xv0 = bf2f(p[tid]);       xv1 = bf2f(p[tid + 128]);
        xv2 = bf2f(p[tid + 256]); xv3 = bf2f(p[tid + 384]);
    }

    for (int t = 0; t < L; ++t) {
        float a0 = 0.f, a1 = 0.f, a2 = 0.f, a3 = 0.f;
        const float* hq = &h_s[ks * 32];
#pragma unroll
        for (int k = 0; k < 32; k += 4) {
            float4 h4 = *(const float4*)(hq + k);
            a0 += w[0][k] * h4.x + w[0][k+1] * h4.y + w[0][k+2] * h4.z + w[0][k+3] * h4.w;
            a1 += w[1][k] * h4.x + w[1][k+1] * h4.y + w[1][k+2] * h4.z + w[1][k+3] * h4.w;
            a2 += w[2][k] * h4.x + w[2][k+1] * h4.y + w[2][k+2] * h4.z + w[2][k+3] * h4.w;
            a3 += w[3][k] * h4.x + w[3][k+1] * h4.y + w[3][k+2] * h4.z + w[3][k+3] * h4.w;
        }
        gp[ks][rr]       = a0;
        gp[ks][rr + 128] = a1;
        gp[ks][rr + 256] = a2;
        gp[ks][rr + 384] = a3;
        LDS_BARRIER();

        if (tid < HD) {
            float gi = xv0 + ((gp[0][tid]       + gp[1][tid])       + (gp[2][tid]       + gp[3][tid]));
            float gf = xv1 + ((gp[0][tid + 128] + gp[1][tid + 128]) + (gp[2][tid + 128] + gp[3][tid + 128]));
            float gg = xv2 + ((gp[0][tid + 256] + gp[1][tid + 256]) + (gp[2][tid + 256] + gp[3][tid + 256]));
            float go = xv3 + ((gp[0][tid + 384] + gp[1][tid + 384]) + (gp[2][tid + 384] + gp[3][tid + 384]));

            int ttn = (t + 1 < L) ? (tt + step) : tt;
            const unsigned short* p = xgb + (size_t)ttn * 1024;
            xv0 = bf2f(p[tid]);       xv1 = bf2f(p[tid + 128]);
            xv2 = bf2f(p[tid + 256]); xv3 = bf2f(p[tid + 384]);

            float ig = sigf(gi);
            float fg = sigf(gf);
            float G  = tanh_f(gg);
            float og = sigf(go);
            c = fg * c + ig * G;
            float hn = og * tanh_f(c);
            h_s[tid] = hn;
            hkeep = hn;
            if (hs) hs[(size_t)(bl * T_LEN + tt) * 256 + dir * HD + tid] = f2bf(hn);
        }
        LDS_BARRIER();
        tt += step;
    }
    if (hTf && tid < HD) {
        (dir ? hTb : hTf)[(size_t)(bOff + bl) * HD + tid] = hkeep;
    }
}

// ---------- final FC + log_softmax ----------
__global__ __launch_bounds__(256)
void fc_lsm(const float* __restrict__ hTf, const float* __restrict__ hTb,
            const float* __restrict__ Wfc, const float* __restrict__ bfc,
            float* __restrict__ out)
{
    int b = threadIdx.x;
    const float* hb = hTb + (size_t)b * HD;
    const float* hf = hTf + (size_t)b * HD;
    float l[NC];
#pragma unroll
    for (int cc = 0; cc < NC; ++cc) {
        const float* wr = Wfc + cc * 256;
        float acc = bfc[cc];
        for (int k = 0; k < HD; k += 4) {
            acc += hb[k] * wr[k] + hb[k + 1] * wr[k + 1]
                 + hb[k + 2] * wr[k + 2] + hb[k + 3] * wr[k + 3];
            acc += hf[k] * wr[128 + k] + hf[k + 1] * wr[128 + k + 1]
                 + hf[k + 2] * wr[128 + k + 2] + hf[k + 3] * wr[128 + k + 3];
        }
        l[cc] = acc;
    }
    float m = l[0];
#pragma unroll
    for (int cc = 1; cc < NC; ++cc) m = fmaxf(m, l[cc]);
    float s = 0.0f;
#pragma unroll
    for (int cc = 0; cc < NC; ++cc) s += __expf(l[cc] - m);
    float lg = m + logf(s);
#pragma unroll
    for (int cc = 0; cc < NC; ++cc) out[(size_t)b * NC + cc] = l[cc] - lg;
}

extern "C" void kernel_launch(void* const* d_in, const int* in_sizes, int n_in,
                              void* d_out, int out_size, void* d_ws, size_t ws_size,
                              hipStream_t stream)
{
    const float* X    = (const float*)d_in[0];
    const int*   len  = (const int*)d_in[1];
    const float* Wih0 = (const float*)d_in[2];   // (2,512,64)  -> (1024,64)
    const float* Whh0 = (const float*)d_in[3];   // (2,512,128)
    const float* b0   = (const float*)d_in[4];   // (2,512) -> (1024)
    const float* Wih1 = (const float*)d_in[5];   // (2,512,256) -> (1024,256)
    const float* Whh1 = (const float*)d_in[6];
    const float* b1   = (const float*)d_in[7];
    const float* Wfc  = (const float*)d_in[8];   // (12,256)
    const float* bfc  = (const float*)d_in[9];   // (12)
    float* out = (float*)d_out;

    const size_t xg_b = (size_t)ROWS * 1024 * 2;   // 128 MB
    const size_t h1_b = (size_t)ROWS * 256 * 2;    // 32 MB
    const size_t hT_b = (size_t)B_ALL * HD * 4;    // 128 KB each
    const size_t sp_b = (size_t)(1024 * 64 * 2 + 1024 * 256 * 2) * 2;  // 2.5 MB

    // Overlap path needs a second xg buffer.
    const size_t need_big = 2 * xg_b + h1_b + 2 * hT_b + sp_b;
    bool big = (ws_size >= need_big);

    char* ws = (char*)d_ws;
    size_t off = 0;
    unsigned short* xgA = (unsigned short*)(ws + off); off += xg_b;
    unsigned short* xgB = big ? (unsigned short*)(ws + off) : xgA;
    if (big) off += xg_b;
    unsigned short* h1 = (unsigned short*)(ws + off); off += h1_b;
    float* hTf = (float*)(ws + off); off += hT_b;
    float* hTb = (float*)(ws + off); off += hT_b;
    unsigned short* W0hi = (unsigned short*)(ws + off); off += 1024 * 64 * 2;
    unsigned short* W0lo = (unsigned short*)(ws + off); off += 1024 * 64 * 2;
    unsigned short* W1hi = (unsigned short*)(ws + off); off += 1024 * 256 * 2;
    unsigned short* W1lo = (unsigned short*)(ws + off); off += 1024 * 256 * 2;

    split_w<<<(1024 * 64 + 255) / 256, 256, 0, stream>>>(Wih0, W0hi, W0lo, 1024 * 64);
    split_w<<<(1024 * 256 + 255) / 256, 256, 0, stream>>>(Wih1, W1hi, W1lo, 1024 * 256);

    const int* lc0 = len;
    const int* lc1 = len + BCH;
    const float* Xc0 = X;
    const float* Xc1 = X + (size_t)BCH * T_LEN * D_INP;

    if (big) {
        // 1. layer0 gemm chunk0 -> xgA
        gates_gemm_mfma<3, float><<<dim3(ROWS / 128, 8), 256, 0, stream>>>(
            Xc0, W0hi, W0lo, b0, lc0, xgA, D_INP);
        // 2. rec L0 c0: xgA -> h1
        lstm_rec<<<256, 512, 0, stream>>>(xgA, xgA, Whh0, Whh0, lc0, lc0,
                                          h1, h1, nullptr, nullptr, nullptr, nullptr, 0, 0);
        // 3. layer1 gemm chunk0: h1 -> xgB
        gates_gemm_mfma<2, unsigned short><<<dim3(ROWS / 128, 8), 256, 0, stream>>>(
            h1, W1hi, W1lo, b1, lc0, xgB, 2 * HD);
        // 4. layer0 gemm chunk1 -> xgA (xgA free after step 2)
        gates_gemm_mfma<3, float><<<dim3(ROWS / 128, 8), 256, 0, stream>>>(
            Xc1, W0hi, W0lo, b0, lc1, xgA, D_INP);
        // 5. COMBINED: role0 = rec L1 c0 (xgB -> hT), role1 = rec L0 c1 (xgA -> h1)
        //    512 blocks -> 2 independent blocks/CU, decoupled barriers.
        lstm_rec<<<512, 512, 0, stream>>>(xgB, xgA, Whh1, Whh0, lc0, lc1,
                                          nullptr, h1, hTf, hTb, nullptr, nullptr, 0, 0);
        // 6. layer1 gemm chunk1: h1 -> xgB (xgB free after step 5)
        gates_gemm_mfma<2, unsigned short><<<dim3(ROWS / 128, 8), 256, 0, stream>>>(
            h1, W1hi, W1lo, b1, lc1, xgB, 2 * HD);
        // 7. rec L1 c1: xgB -> hT
        lstm_rec<<<256, 512, 0, stream>>>(xgB, xgB, Whh1, Whh1, lc1, lc1,
                                          nullptr, nullptr, hTf, hTb, nullptr, nullptr, BCH, BCH);
    } else {
        // exact R5 fallback (proven 2365 µs)
        for (int ch = 0; ch < 2; ++ch) {
            const int* lc = (ch == 0) ? lc0 : lc1;
            const float* Xc = (ch == 0) ? Xc0 : Xc1;
            gates_gemm_mfma<3, float><<<dim3(ROWS / 128, 8), 256, 0, stream>>>(
                Xc, W0hi, W0lo, b0, lc, xgA, D_INP);
            lstm_rec<<<256, 512, 0, stream>>>(xgA, xgA, Whh0, Whh0, lc, lc,
                                              h1, h1, nullptr, nullptr, nullptr, nullptr, 0, 0);
            gates_gemm_mfma<2, unsigned short><<<dim3(ROWS / 128, 8), 256, 0, stream>>>(
                h1, W1hi, W1lo, b1, lc, xgA, 2 * HD);
            lstm_rec<<<256, 512, 0, stream>>>(xgA, xgA, Whh1, Whh1, lc, lc,
                                              nullptr, nullptr, hTf, hTb, nullptr, nullptr,
                                              ch * BCH, ch * BCH);
        }
    }
    fc_lsm<<<1, 256, 0, stream>>>(hTf, hTb, Wfc, bfc, out);
}